// Round 3
// baseline (338.589 us; speedup 1.0000x reference)
//
#include <hip/hip_runtime.h>
#include <hip/hip_bf16.h>

// TrendEncoder: histogram (B=4096, S=200 -> 256 bins) + 256-step LSTM (H=64).
// Round 8: software anti-phase dual-stream. R6/R7 showed co-resident waves
// (shared OR independent barriers) hide NOTHING: identical blocks phase-lock.
// R5's 1340 cyc/step = ~710 issue + ~630 structurally unhideable latency:
// post-barrier ds_read+MFMA ramp and pre-barrier write+drain, with no
// independent in-wave work to fill them.
// Fix: each block runs TWO 8-row recurrences (X=rows 0-7, Y=rows 8-15) at
// HALF-STEP OFFSET inside the same waves, two barriers per interval:
//   [S] readX, actY(prev accY), writeY, mfmaX   |  [M] readY, actX, writeX, mfmaY
// Every read+MFMA latency window is statically overlapped with the other
// stream's trans-heavy act. Both streams advance 1 step/interval.
// 8-row streams use padded M=16 MFMA (A rows 0-7 real); act compacted to
// 2 units/lane via shfl_xor(32) redistribution (verified in R7):
//   quad0: rows 0,1   quad1: rows 4,5   quad2: rows 2,3   quad3: rows 6,7

#define B_S     200
#define B_T     256
#define ROWS    16    // block batch rows = 8 (X) + 8 (Y)
#define THREADS 256
#define HS      72    // h row stride (fp16 elems) = 144 B
#define LOG2E   1.4426950408889634f

typedef __attribute__((ext_vector_type(8))) _Float16 half8;
typedef __attribute__((ext_vector_type(4))) float float4_t;

__device__ __forceinline__ float load_f(const void* p, int i, int isb) {
    if (isb) {
        unsigned short u = ((const unsigned short*)p)[i];
        return __uint_as_float(((unsigned int)u) << 16);
    }
    return ((const float*)p)[i];
}

__global__ __launch_bounds__(THREADS)
void trend_encoder_kernel(const void* __restrict__ time_,
                          const int*  __restrict__ length,
                          const void* __restrict__ ptime_,
                          const void* __restrict__ wih_,
                          const void* __restrict__ whh_,
                          const void* __restrict__ bih_,
                          const void* __restrict__ bhh_,
                          void* __restrict__ out_) {
    __shared__ __align__(16) float x_t[B_T * ROWS];            // [t][row], 16 KB
    __shared__ __align__(16) _Float16 hX[2][16 * HS];          // X h, dbuf
    __shared__ __align__(16) _Float16 hY[2][16 * HS];          // Y h, dbuf
    __shared__ int flag_sh;

    const int tid  = threadIdx.x;
    const int wv   = tid >> 6;        // wave 0..3 = hidden-col tile
    const int lane = tid & 63;
    const int m    = lane & 15;
    const int quad = lane >> 4;
    const int b0   = blockIdx.x * ROWS;

    // ---- dtype probe (wave 0): W_ih ~ U(-0.125,0.125); f32 reinterpreted as
    // bf16 words goes far out of range with overwhelming probability.
    if (tid < 64) {
        unsigned short u = ((const unsigned short*)wih_)[tid];
        float v = __uint_as_float(((unsigned int)u) << 16);
        int bad = !(v > -0.2f && v < 0.2f);
        unsigned long long bm = __ballot(bad);
        if (lane == 0) flag_sh = (bm == 0ULL) ? 1 : 0;
    }
    for (int i = tid; i < B_T * ROWS; i += THREADS) x_t[i] = 0.0f;
    // zero all 4 h buffers fully: rows 8-15 are never written afterwards
    for (int i = tid; i < 2 * 16 * HS; i += THREADS) (&hX[0][0])[i] = (_Float16)0.0f;
    for (int i = tid; i < 2 * 16 * HS; i += THREADS) (&hY[0][0])[i] = (_Float16)0.0f;
    __syncthreads();
    const int isb = flag_sh;

    // ---- histogram: pos = trunc((pt - t)*0.25), add at bin 255-pos (transposed)
    for (int e = tid; e < ROWS * B_S; e += THREADS) {
        int row  = e / B_S;
        int s    = e - row * B_S;
        int grow = b0 + row;
        if (s < length[grow]) {
            float pt = load_f(ptime_, grow, isb);
            float tv = load_f(time_, grow * B_S + s, isb);
            int pos = (int)((pt - tv) * 0.25f);
            if (pos >= 0 && pos < B_T)
                atomicAdd(&x_t[(B_T - 1 - pos) * ROWS + row], 1.0f);
        }
    }

    // ---- resident weights (fp16, gate-prescaled). tile tt = gate (i,f,g,o),
    // col n = 16wv + 64tt + m.  B-frag: n = lane&15, k = 32c + 8*quad + j.
    const float gsc[4] = {-LOG2E, -LOG2E, 2.0f * LOG2E, -LOG2E};
    half8 bw[4][2];
    float wihv[4], biasv[4];
    #pragma unroll
    for (int tt = 0; tt < 4; ++tt) {
        int n = 16 * wv + 64 * tt + m;
        float s = gsc[tt];
        wihv[tt]  = load_f(wih_, n, isb) * s;
        biasv[tt] = (load_f(bih_, n, isb) + load_f(bhh_, n, isb)) * s;
        #pragma unroll
        for (int c = 0; c < 2; ++c) {
            half8 v;
            #pragma unroll
            for (int j = 0; j < 8; ++j)
                v[j] = (_Float16)(load_f(whh_, n * 64 + 32 * c + 8 * quad + j, isb) * s);
            bw[tt][c] = v;
        }
    }

    const int aoff  = m * HS + 8 * quad;                 // A-frag base (elems)
    const int kcol  = 16 * wv + m;                       // owned unit column
    const int row0  = 4 * (quad & 1) + 2 * (quad >> 1);  // local rows after redist
    const int yxofs = (8 + 4 * quad) & 15;               // Y x-broadcast row base
    float cX0 = 0.f, cX1 = 0.f, cY0 = 0.f, cY1 = 0.f;
    float hXr0 = 0.f, hXr1 = 0.f, hYr0 = 0.f, hYr1 = 0.f;

    __syncthreads();   // S_0: histogram + h init + weights visible

    // fused in-lane activation (state regs CR/HR explicit; RI = local row)
    #define ACT(CR, HR, G0, G1, G2, G3, WBP, RI)                              \
    {                                                                         \
        float A_  = __builtin_amdgcn_exp2f(G0);                               \
        float F_  = __builtin_amdgcn_exp2f(G1);                               \
        float Bv_ = __builtin_amdgcn_exp2f(G2);                               \
        float t1_    = (1.0f + A_) * (Bv_ + 1.0f);                            \
        float oneF_  = 1.0f + F_;                                             \
        float numer_ = fmaf(CR, t1_, oneF_ * (Bv_ - 1.0f));                   \
        float denom_ = oneF_ * t1_;                                           \
        CR = numer_ * __builtin_amdgcn_rcpf(denom_);                          \
        float D_  = __builtin_amdgcn_exp2f(G3);                               \
        float cs_ = fminf(CR * (2.0f * LOG2E), 126.0f);                       \
        float E_  = __builtin_amdgcn_exp2f(cs_);                              \
        float h_  = (E_ - 1.0f) * __builtin_amdgcn_rcpf((1.0f + D_) * (E_ + 1.0f)); \
        HR = h_;                                                              \
        WBP[(RI) * HS + kcol] = (_Float16)h_;                                 \
    }

    // redistribute 8 real C-rows over all 64 lanes (2 units/lane)
    #define REDIST(ACC, GA, GB)                                               \
    {                                                                         \
        _Pragma("unroll")                                                     \
        for (int tt = 0; tt < 4; ++tt) {                                      \
            float x2_ = __shfl_xor(ACC[tt][2], 32);                           \
            float x3_ = __shfl_xor(ACC[tt][3], 32);                           \
            GA[tt] = (quad < 2) ? ACC[tt][0] : x2_;                           \
            GB[tt] = (quad < 2) ? ACC[tt][1] : x3_;                           \
        }                                                                     \
    }

    #define GATES(ACC, A0, A1, XV)                                            \
    {                                                                         \
        _Pragma("unroll")                                                     \
        for (int tt = 0; tt < 4; ++tt) {                                      \
            float4_t a_;                                                      \
            _Pragma("unroll")                                                 \
            for (int r = 0; r < 4; ++r) a_[r] = fmaf(XV[r], wihv[tt], biasv[tt]); \
            a_ = __builtin_amdgcn_mfma_f32_16x16x32_f16(A0, bw[tt][0], a_, 0, 0, 0); \
            a_ = __builtin_amdgcn_mfma_f32_16x16x32_f16(A1, bw[tt][1], a_, 0, 0, 0); \
            ACC[tt] = a_;                                                     \
        }                                                                     \
    }

    // prologue: accY = gY^(0) = x_0*wih + b  (hY^(0)=0, no mfma needed)
    float4_t accY[4];
    {
        float4_t xv0 = *(const float4_t*)&x_t[yxofs];
        #pragma unroll
        for (int tt = 0; tt < 4; ++tt) {
            #pragma unroll
            for (int r = 0; r < 4; ++r) accY[tt][r] = fmaf(xv0[r], wihv[tt], biasv[tt]);
        }
    }

    for (int t = 0; t < B_T; ++t) {
        const int pr = t & 1, pw = pr ^ 1;

        // X A-frags (h_X^(t), published at S_t)
        half8 ax0 = *(const half8*)&hX[pr][aoff];
        half8 ax1 = *(const half8*)&hX[pr][aoff + 32];

        // act Y: gY^(t) -> hY^(t+1); issues while ax0/ax1 + mfmaX in flight
        {
            float gA[4], gB[4];
            REDIST(accY, gA, gB);
            _Float16* wb = hY[pw];
            ACT(cY0, hYr0, gA[0], gA[1], gA[2], gA[3], wb, row0);
            ACT(cY1, hYr1, gB[0], gB[1], gB[2], gB[3], wb, row0 + 1);
        }

        // X gates: gX^(t)
        float4_t accX[4];
        {
            float4_t xvX = *(const float4_t*)&x_t[t * ROWS + quad * 4];
            GATES(accX, ax0, ax1, xvX);
        }
        __syncthreads();   // M_t: publishes hY^(t+1)

        // Y A-frags (h_Y^(t+1))
        half8 ay0 = *(const half8*)&hY[pw][aoff];
        half8 ay1 = *(const half8*)&hY[pw][aoff + 32];

        // act X: gX^(t) -> hX^(t+1); issues while ay0/ay1 + mfmaY in flight
        {
            float gA[4], gB[4];
            REDIST(accX, gA, gB);
            _Float16* wb = hX[pw];
            ACT(cX0, hXr0, gA[0], gA[1], gA[2], gA[3], wb, row0);
            ACT(cX1, hXr1, gB[0], gB[1], gB[2], gB[3], wb, row0 + 1);
        }

        // Y gates for step t+1 (t=255: clamped x, result unused)
        {
            int tn = (t + 1 < B_T) ? t + 1 : t;
            float4_t xvY = *(const float4_t*)&x_t[tn * ROWS + yxofs];
            GATES(accY, ay0, ay1, xvY);
        }
        __syncthreads();   // S_{t+1}: publishes hX^(t+1)
    }
    #undef ACT
    #undef REDIST
    #undef GATES

    // ---- epilogue: X rows b0+row0+{0,1}, Y rows b0+8+row0+{0,1}
    {
        int oX = (b0 + row0) * 64 + kcol;
        int oY = (b0 + 8 + row0) * 64 + kcol;
        if (isb) {
            ((__hip_bfloat16*)out_)[oX]      = __float2bfloat16(hXr0);
            ((__hip_bfloat16*)out_)[oX + 64] = __float2bfloat16(hXr1);
            ((__hip_bfloat16*)out_)[oY]      = __float2bfloat16(hYr0);
            ((__hip_bfloat16*)out_)[oY + 64] = __float2bfloat16(hYr1);
        } else {
            ((float*)out_)[oX]      = hXr0;
            ((float*)out_)[oX + 64] = hXr1;
            ((float*)out_)[oY]      = hYr0;
            ((float*)out_)[oY + 64] = hYr1;
        }
    }
}

extern "C" void kernel_launch(void* const* d_in, const int* in_sizes, int n_in,
                              void* d_out, int out_size, void* d_ws, size_t ws_size,
                              hipStream_t stream) {
    const void* time_  = d_in[0];
    const int*  length = (const int*)d_in[1];
    const void* ptime  = d_in[2];
    const void* wih    = d_in[3];
    const void* whh    = d_in[4];
    const void* bih    = d_in[5];
    const void* bhh    = d_in[6];

    const int B = in_sizes[1];   // 4096
    trend_encoder_kernel<<<dim3(B / ROWS), dim3(THREADS), 0, stream>>>(
        time_, length, ptime, wih, whh, bih, bhh, d_out);
}

// Round 4
// 265.020 us; speedup vs baseline: 1.2776x; 1.2776x over previous
//
#include <hip/hip_runtime.h>
#include <hip/hip_bf16.h>

// TrendEncoder: histogram (B=4096, S=200 -> 256 bins) + 256-step LSTM (H=64).
// Round 9: BARRIER-FREE in-wave recurrence. R5-R8 established that every
// barrier crossing costs ~630 unhideable cycles and no co-scheduling fills it
// (R6 lockstep co-waves, R7 phase-locked blocks, R8 anti-phase: all failed).
// Root cause: units split across waves forces h through LDS + __syncthreads
// each step. Fix: each wave owns 4 batch rows x ALL 64 units -> recurrence
// never leaves the wave; zero barriers in the 256-step loop.
//   - Real rows at M-index {0,4,8,12}: C real data at reg r=0 of every lane
//     -> 4 acts/lane (one per 16-col group u), no shuffles, no divergence.
//   - A pad rows stay zero in LDS -> pad C rows stay zero (acc[r!=0]=0 once).
//   - Step-to-step h hop = same-wave ds_write -> ds_read (DS pipe is in-order
//     per wave; no barrier needed). h LDS XOR-swizzled (byte bits4-6 ^= row&7)
//     so the stride-128B ds_read_b128 is 2-way (free) not 16-way.
//   - 32 MFMAs/step/wave (4x duplication, 25% M-eff) - cheap, separate pipe.
//   - W_hh resident in regs: bw[4g][4u][2c] half8 = 128 VGPR; ~230 total,
//     __launch_bounds__(256,1) -> 1 wave/SIMD (by design; no TLP needed).
//   - Acts in pairs (u01, u23); na0 read issued mid-step (needs only units
//     0-31 = groups 0,1) so its latency hides under pair-B work.

#define B_S     200
#define B_T     256
#define ROWS    16    // batch rows per block (4 waves x 4 rows)
#define THREADS 256
#define LOG2E   1.4426950408889634f

typedef __attribute__((ext_vector_type(8))) _Float16 half8;
typedef __attribute__((ext_vector_type(4))) float float4_t;

__device__ __forceinline__ float load_f(const void* p, int i, int isb) {
    if (isb) {
        unsigned short u = ((const unsigned short*)p)[i];
        return __uint_as_float(((unsigned int)u) << 16);
    }
    return ((const float*)p)[i];
}

__global__ __launch_bounds__(THREADS, 1)
void trend_encoder_kernel(const void* __restrict__ time_,
                          const int*  __restrict__ length,
                          const void* __restrict__ ptime_,
                          const void* __restrict__ wih_,
                          const void* __restrict__ whh_,
                          const void* __restrict__ bih_,
                          const void* __restrict__ bhh_,
                          void* __restrict__ out_) {
    __shared__ __align__(16) float x_t[B_T * ROWS];          // [t][row], 16 KB
    __shared__ __align__(16) _Float16 h_lds[4][16 * 64];     // per-wave swizzled h
    __shared__ int flag_sh;

    const int tid  = threadIdx.x;
    const int wv   = tid >> 6;        // wave 0..3 (independent after init)
    const int lane = tid & 63;
    const int m    = lane & 15;
    const int q    = lane >> 4;       // quad = this lane's local batch row
    const int b0   = blockIdx.x * ROWS;

    // ---- dtype probe (wave 0): W_ih ~ U(-0.125,0.125); f32 reinterpreted as
    // bf16 words goes far out of range with overwhelming probability.
    if (tid < 64) {
        unsigned short u = ((const unsigned short*)wih_)[tid];
        float v = __uint_as_float(((unsigned int)u) << 16);
        int bad = !(v > -0.2f && v < 0.2f);
        unsigned long long bm = __ballot(bad);
        if (lane == 0) flag_sh = (bm == 0ULL) ? 1 : 0;
    }
    for (int i = tid; i < B_T * ROWS; i += THREADS) x_t[i] = 0.0f;
    // zero all h: pad rows (R % 4 != 0) must stay 0 forever (A pad rows)
    for (int i = tid; i < 4 * 16 * 64; i += THREADS)
        (&h_lds[0][0])[i] = (_Float16)0.0f;
    __syncthreads();
    const int isb = flag_sh;

    // ---- histogram: pos = trunc((pt - t)*0.25), add at bin 255-pos (transposed)
    for (int e = tid; e < ROWS * B_S; e += THREADS) {
        int row  = e / B_S;
        int s    = e - row * B_S;
        int grow = b0 + row;
        if (s < length[grow]) {
            float pt = load_f(ptime_, grow, isb);
            float tv = load_f(time_, grow * B_S + s, isb);
            int pos = (int)((pt - tv) * 0.25f);
            if (pos >= 0 && pos < B_T)
                atomicAdd(&x_t[(B_T - 1 - pos) * ROWS + row], 1.0f);
        }
    }

    // ---- resident weights (fp16, gate-prescaled). Gate g, unit group u:
    // gate-col n = 64g + 16u + m. B-frag: n = lane&15, k = 32c + 8q + j.
    const float gsc[4] = {-LOG2E, -LOG2E, 2.0f * LOG2E, -LOG2E};
    half8 bw[4][4][2];                 // [g][u][c] = 128 VGPR
    float wihv[4][4], biasv[4][4];
    #pragma unroll
    for (int g = 0; g < 4; ++g) {
        #pragma unroll
        for (int u = 0; u < 4; ++u) {
            int n = 64 * g + 16 * u + m;
            float s = gsc[g];
            wihv[g][u]  = load_f(wih_, n, isb) * s;
            biasv[g][u] = (load_f(bih_, n, isb) + load_f(bhh_, n, isb)) * s;
            #pragma unroll
            for (int c = 0; c < 2; ++c) {
                half8 v;
                #pragma unroll
                for (int j = 0; j < 8; ++j)
                    v[j] = (_Float16)(load_f(whh_, n * 64 + 32 * c + 8 * q + j, isb) * s);
                bw[g][u][c] = v;
            }
        }
    }

    // ---- swizzled h addressing: element (R,c) at 64R + (c&7) + (((c>>3)^(R&7))<<3)
    _Float16* hw = h_lds[wv];
    const int xrow = 4 * wv + q;                 // local batch row in block
    const int mh   = m >> 3;
    const int wsw  = 4 * (q & 1);                // (R=4q)&7
    const int wbase = 256 * q + (m & 7);
    const int wi0 = wbase + ((((0 + mh) ^ wsw) & 7) << 3);   // write c=16*0+m
    const int wi1 = wbase + ((((2 + mh) ^ wsw) & 7) << 3);   // write c=16*1+m
    const int wi2 = wbase + ((((4 + mh) ^ wsw) & 7) << 3);   // write c=16*2+m
    const int wi3 = wbase + ((((6 + mh) ^ wsw) & 7) << 3);   // write c=16*3+m
    const int ra0 = 64 * m + ((q ^ (m & 7)) << 3);           // read k=8q..8q+7
    const int ra1 = 64 * m + (((4 + q) ^ (m & 7)) << 3);     // read k=32+8q..

    __syncthreads();   // x_t + zeroed h visible. NO barriers after this point.

    #define ACT(CR, HR, G0, G1, G2, G3)                                       \
    {                                                                         \
        float A_  = __builtin_amdgcn_exp2f(G0);                               \
        float F_  = __builtin_amdgcn_exp2f(G1);                               \
        float Bv_ = __builtin_amdgcn_exp2f(G2);                               \
        float t1_    = (1.0f + A_) * (Bv_ + 1.0f);                            \
        float oneF_  = 1.0f + F_;                                             \
        float numer_ = fmaf(CR, t1_, oneF_ * (Bv_ - 1.0f));                   \
        float denom_ = oneF_ * t1_;                                           \
        CR = numer_ * __builtin_amdgcn_rcpf(denom_);                          \
        float D_  = __builtin_amdgcn_exp2f(G3);                               \
        float cs_ = fminf(CR * (2.0f * LOG2E), 126.0f);                       \
        float E_  = __builtin_amdgcn_exp2f(cs_);                              \
        HR = (E_ - 1.0f) * __builtin_amdgcn_rcpf((1.0f + D_) * (E_ + 1.0f));  \
    }

    half8 a0 = 0, a1 = 0;             // h^0 = 0 fragments
    float xb = x_t[xrow];             // x[t=0] for this lane's row
    float c0 = 0.f, c1 = 0.f, c2 = 0.f, c3 = 0.f;
    float h0 = 0.f, h1 = 0.f, h2 = 0.f, h3 = 0.f;
    float4_t accA[4], accB[4];        // [g]; r=0 real, r=1..3 stay 0 forever
    #pragma unroll
    for (int g = 0; g < 4; ++g) { accA[g] = (float4_t)0.0f; accB[g] = (float4_t)0.0f; }

    for (int t = 0; t < B_T; ++t) {
        // ---- pair A: unit groups u=0,1 ----
        #pragma unroll
        for (int g = 0; g < 4; ++g) accA[g][0] = fmaf(xb, wihv[g][0], biasv[g][0]);
        #pragma unroll
        for (int g = 0; g < 4; ++g) accB[g][0] = fmaf(xb, wihv[g][1], biasv[g][1]);
        #pragma unroll
        for (int g = 0; g < 4; ++g)
            accA[g] = __builtin_amdgcn_mfma_f32_16x16x32_f16(a0, bw[g][0][0], accA[g], 0, 0, 0);
        #pragma unroll
        for (int g = 0; g < 4; ++g)
            accB[g] = __builtin_amdgcn_mfma_f32_16x16x32_f16(a0, bw[g][1][0], accB[g], 0, 0, 0);
        #pragma unroll
        for (int g = 0; g < 4; ++g)
            accA[g] = __builtin_amdgcn_mfma_f32_16x16x32_f16(a1, bw[g][0][1], accA[g], 0, 0, 0);
        #pragma unroll
        for (int g = 0; g < 4; ++g)
            accB[g] = __builtin_amdgcn_mfma_f32_16x16x32_f16(a1, bw[g][1][1], accB[g], 0, 0, 0);

        ACT(c0, h0, accA[0][0], accA[1][0], accA[2][0], accA[3][0]);
        hw[wi0] = (_Float16)h0;
        ACT(c1, h1, accB[0][0], accB[1][0], accB[2][0], accB[3][0]);
        hw[wi1] = (_Float16)h1;
        // h^{t+1} units 0..31 (groups 0,1) now queued in DS pipe; read them.
        // Same-wave DS ops complete in order -> no barrier needed. Latency
        // hides under pair-B MFMAs + acts below.
        half8 na0 = *(const half8*)&hw[ra0];

        // ---- pair B: unit groups u=2,3 (a0/a1 still h^t in regs) ----
        #pragma unroll
        for (int g = 0; g < 4; ++g) accA[g][0] = fmaf(xb, wihv[g][2], biasv[g][2]);
        #pragma unroll
        for (int g = 0; g < 4; ++g) accB[g][0] = fmaf(xb, wihv[g][3], biasv[g][3]);
        #pragma unroll
        for (int g = 0; g < 4; ++g)
            accA[g] = __builtin_amdgcn_mfma_f32_16x16x32_f16(a0, bw[g][2][0], accA[g], 0, 0, 0);
        #pragma unroll
        for (int g = 0; g < 4; ++g)
            accB[g] = __builtin_amdgcn_mfma_f32_16x16x32_f16(a0, bw[g][3][0], accB[g], 0, 0, 0);
        #pragma unroll
        for (int g = 0; g < 4; ++g)
            accA[g] = __builtin_amdgcn_mfma_f32_16x16x32_f16(a1, bw[g][2][1], accA[g], 0, 0, 0);
        #pragma unroll
        for (int g = 0; g < 4; ++g)
            accB[g] = __builtin_amdgcn_mfma_f32_16x16x32_f16(a1, bw[g][3][1], accB[g], 0, 0, 0);

        ACT(c2, h2, accA[0][0], accA[1][0], accA[2][0], accA[3][0]);
        hw[wi2] = (_Float16)h2;
        ACT(c3, h3, accB[0][0], accB[1][0], accB[2][0], accB[3][0]);
        hw[wi3] = (_Float16)h3;
        half8 na1 = *(const half8*)&hw[ra1];     // units 32..63 (groups 2,3)

        int tn = (t + 1 < B_T) ? t + 1 : t;      // t=255: dummy (unused)
        float nxb = x_t[tn * ROWS + xrow];
        a0 = na0; a1 = na1; xb = nxb;
    }
    #undef ACT

    // ---- epilogue: this lane's row = b0 + 4wv + q, units 16u+m
    {
        int ob = (b0 + 4 * wv + q) * 64 + m;
        if (isb) {
            ((__hip_bfloat16*)out_)[ob]      = __float2bfloat16(h0);
            ((__hip_bfloat16*)out_)[ob + 16] = __float2bfloat16(h1);
            ((__hip_bfloat16*)out_)[ob + 32] = __float2bfloat16(h2);
            ((__hip_bfloat16*)out_)[ob + 48] = __float2bfloat16(h3);
        } else {
            ((float*)out_)[ob]      = h0;
            ((float*)out_)[ob + 16] = h1;
            ((float*)out_)[ob + 32] = h2;
            ((float*)out_)[ob + 48] = h3;
        }
    }
}

extern "C" void kernel_launch(void* const* d_in, const int* in_sizes, int n_in,
                              void* d_out, int out_size, void* d_ws, size_t ws_size,
                              hipStream_t stream) {
    const void* time_  = d_in[0];
    const int*  length = (const int*)d_in[1];
    const void* ptime  = d_in[2];
    const void* wih    = d_in[3];
    const void* whh    = d_in[4];
    const void* bih    = d_in[5];
    const void* bhh    = d_in[6];

    const int B = in_sizes[1];   // 4096
    trend_encoder_kernel<<<dim3(B / ROWS), dim3(THREADS), 0, stream>>>(
        time_, length, ptime, wih, whh, bih, bhh, d_out);
}

// Round 5
// 191.938 us; speedup vs baseline: 1.7641x; 1.3808x over previous
//
#include <hip/hip_runtime.h>
#include <hip/hip_bf16.h>

// TrendEncoder: histogram (B=4096, S=200 -> 256 bins) + 256-step LSTM (H=64).
// Round 10: R7 structure (2 independent blocks/CU) MINUS the shfl overhead,
// PLUS explicit phase stagger.
//  Synthesis R5-R9: per-SIMD issue ~600-750 cyc/step (trans-dominated) in all
//  layouts; remaining ~600-800 cyc is latency only a DIFFERENTLY-PHASED
//  co-resident wave can fill. R6/R8: shared barrier -> lockstep. R7: two
//  independent blocks but identical start phase -> stall points coincide for
//  all 256 steps (issue 980, coincident stall 800). R9: 1 wave/SIMD -> no
//  hiding at all. Fix here:
//  (a) real batch rows at M-indices {0,1,4,5,8,9,12,13} (batch 2q+r <-> M row
//      4q+r): every lane's C regs r=0,1 are real -> 2 ACTs/lane across all 64
//      lanes, NO shfl_xor (R7's bpermutes are off the critical path for good).
//  (b) phase stagger: hash(blockIdx)&3 x 256-cyc s_sleep after init. Offsets
//      persist (identical step durations, independent barriers) -> block A's
//      post-barrier ds_read/MFMA/act stalls filled by block B's issue.
//
// Block = 8 batch rows, 256 threads (4 waves), grid 512 (2 blocks/CU).
// Wave wv owns gate-cols {16wv+64tt}; lane (q,m) activates units
// (batch row 2q+{0,1}, col 16wv+m) in registers.

#define B_S     200
#define B_T     256
#define ROWS    8     // real batch rows per block
#define MR      16    // MFMA M dim (M rows with (R&3)>=2 are zero-pad)
#define THREADS 256
#define HS      72    // h row stride (fp16 elems) = 144 B
#define LOG2E   1.4426950408889634f

typedef __attribute__((ext_vector_type(8))) _Float16 half8;
typedef __attribute__((ext_vector_type(4))) float float4_t;
typedef __attribute__((ext_vector_type(2))) float float2_t;

__device__ __forceinline__ float load_f(const void* p, int i, int isb) {
    if (isb) {
        unsigned short u = ((const unsigned short*)p)[i];
        return __uint_as_float(((unsigned int)u) << 16);
    }
    return ((const float*)p)[i];
}

__global__ __launch_bounds__(THREADS)
void trend_encoder_kernel(const void* __restrict__ time_,
                          const int*  __restrict__ length,
                          const void* __restrict__ ptime_,
                          const void* __restrict__ wih_,
                          const void* __restrict__ whh_,
                          const void* __restrict__ bih_,
                          const void* __restrict__ bhh_,
                          void* __restrict__ out_) {
    __shared__ __align__(16) float x_t[B_T * ROWS];            // [t][row], 8 KB
    __shared__ __align__(16) _Float16 h_sh[2][MR * HS];        // double-buffered
    __shared__ int flag_sh;

    const int tid  = threadIdx.x;
    const int wv   = tid >> 6;        // wave 0..3 = hidden-col tile
    const int lane = tid & 63;
    const int m    = lane & 15;
    const int quad = lane >> 4;
    const int b0   = blockIdx.x * ROWS;

    // ---- dtype probe (wave 0): W_ih ~ U(-0.125,0.125); f32 reinterpreted as
    // bf16 words goes far out of range with overwhelming probability.
    if (tid < 64) {
        unsigned short u = ((const unsigned short*)wih_)[tid];
        float v = __uint_as_float(((unsigned int)u) << 16);
        int bad = !(v > -0.2f && v < 0.2f);
        unsigned long long bm = __ballot(bad);
        if (lane == 0) flag_sh = (bm == 0ULL) ? 1 : 0;
    }
    for (int i = tid; i < B_T * ROWS; i += THREADS) x_t[i] = 0.0f;
    {   // zero BOTH h buffers: pad M rows ((R&3)>=2) are never written again
        _Float16* hz = &h_sh[0][0];
        for (int i = tid; i < 2 * MR * HS; i += THREADS) hz[i] = (_Float16)0.0f;
    }
    __syncthreads();
    const int isb = flag_sh;

    // ---- histogram: pos = trunc((pt - t)*0.25), add at bin 255-pos (transposed)
    for (int e = tid; e < ROWS * B_S; e += THREADS) {
        int row  = e / B_S;
        int s    = e - row * B_S;
        int grow = b0 + row;
        if (s < length[grow]) {
            float pt = load_f(ptime_, grow, isb);
            float tv = load_f(time_, grow * B_S + s, isb);
            int pos = (int)((pt - tv) * 0.25f);
            if (pos >= 0 && pos < B_T)
                atomicAdd(&x_t[(B_T - 1 - pos) * ROWS + row], 1.0f);
        }
    }

    // ---- resident weights (fp16, gate-prescaled). tile tt = gate (i,f,g,o),
    // col n = 16wv + 64tt + m.  B-frag: n = lane&15, k = 32c + 8*quad + j.
    const float gsc[4] = {-LOG2E, -LOG2E, 2.0f * LOG2E, -LOG2E};
    half8 bw[4][2];
    float wihv[4], biasv[4];
    #pragma unroll
    for (int tt = 0; tt < 4; ++tt) {
        int n = 16 * wv + 64 * tt + m;
        float s = gsc[tt];
        wihv[tt]  = load_f(wih_, n, isb) * s;
        biasv[tt] = (load_f(bih_, n, isb) + load_f(bhh_, n, isb)) * s;
        #pragma unroll
        for (int c = 0; c < 2; ++c) {
            half8 v;
            #pragma unroll
            for (int j = 0; j < 8; ++j)
                v[j] = (_Float16)(load_f(whh_, n * 64 + 32 * c + 8 * quad + j, isb) * s);
            bw[tt][c] = v;
        }
    }

    const int aoff = m * HS + 8 * quad;   // A-frag base (elems); M row m
    const int kcol = 16 * wv + m;         // owned unit column
    float creg[2] = {0.f, 0.f};
    float hreg[2] = {0.f, 0.f};
    __syncthreads();   // histogram + h init + weights visible

    // ---- phase stagger: de-phase co-resident blocks so their stall points
    // interleave. Hash covers any plausible block->CU pairing stride.
    {
        unsigned ph = (blockIdx.x * 2654435761u) >> 30;   // 0..3
        #pragma nounroll
        for (unsigned i = 0; i < 4 * ph; ++i) __builtin_amdgcn_s_sleep(1);  // 256 cyc/phase
    }

    // fused in-lane activation for unit (batch row 2q+RR = M row 4q+RR).
    #define ACT(RR, G0, G1, G2, G3)                                           \
    {                                                                         \
        float A  = __builtin_amdgcn_exp2f(G0);          /* exp2(-i*log2e) */  \
        float F  = __builtin_amdgcn_exp2f(G1);          /* exp2(-f*log2e) */  \
        float Bv = __builtin_amdgcn_exp2f(G2);          /* exp2(2g*log2e) */  \
        float t1    = (1.0f + A) * (Bv + 1.0f);                               \
        float oneF  = 1.0f + F;                                               \
        float numer = fmaf(creg[RR], t1, oneF * (Bv - 1.0f));                 \
        float denom = oneF * t1;                                              \
        creg[RR] = numer * __builtin_amdgcn_rcpf(denom);                      \
        float D  = __builtin_amdgcn_exp2f(G3);          /* exp2(-o*log2e) */  \
        float cs = fminf(creg[RR] * (2.0f * LOG2E), 126.0f);  /* inf guard */ \
        float E  = __builtin_amdgcn_exp2f(cs);                                \
        float h  = (E - 1.0f) * __builtin_amdgcn_rcpf((1.0f + D) * (E + 1.0f)); \
        hreg[RR] = h;                                                         \
        wb[(4 * quad + RR) * HS + kcol] = (_Float16)h;                        \
    }

    for (int t = 0; t < B_T; ++t) {
        const int p = t & 1;
        const _Float16* hh = h_sh[p];
        // A fragments (A[m][k], m=lane&15, k=8*quad+j): 2 K-chunks.
        // M row m holds h of batch row 2*(m>>2)+(m&3) for (m&3)<2, else zero.
        half8 a0 = *(const half8*)&hh[aoff];
        half8 a1 = *(const half8*)&hh[aoff + 32];
        // x for this lane's 2 batch rows 2q, 2q+1 (8B aligned)
        float2_t xv = *(const float2_t*)&x_t[t * ROWS + 2 * quad];

        float4_t acc[4];
        #pragma unroll
        for (int tt = 0; tt < 4; ++tt) {
            float4_t a;
            a[0] = fmaf(xv[0], wihv[tt], biasv[tt]);
            a[1] = fmaf(xv[1], wihv[tt], biasv[tt]);
            a[2] = 0.0f;   // pad C rows: A pad rows are zero -> stay 0
            a[3] = 0.0f;
            a = __builtin_amdgcn_mfma_f32_16x16x32_f16(a0, bw[tt][0], a, 0, 0, 0);
            a = __builtin_amdgcn_mfma_f32_16x16x32_f16(a1, bw[tt][1], a, 0, 0, 0);
            acc[tt] = a;
        }

        // activation: regs r=0,1 are real rows for EVERY lane (no shuffles)
        _Float16* wb = h_sh[p ^ 1];
        ACT(0, acc[0][0], acc[1][0], acc[2][0], acc[3][0]);
        ACT(1, acc[0][1], acc[1][1], acc[2][1], acc[3][1]);
        __syncthreads();   // the only barrier per step
    }
    #undef ACT

    // ---- epilogue: final h of the 2 owned units (batch rows 2q, 2q+1)
    #pragma unroll
    for (int rr = 0; rr < 2; ++rr) {
        int o = (b0 + 2 * quad + rr) * 64 + kcol;
        if (isb) ((__hip_bfloat16*)out_)[o] = __float2bfloat16(hreg[rr]);
        else     ((float*)out_)[o] = hreg[rr];
    }
}

extern "C" void kernel_launch(void* const* d_in, const int* in_sizes, int n_in,
                              void* d_out, int out_size, void* d_ws, size_t ws_size,
                              hipStream_t stream) {
    const void* time_  = d_in[0];
    const int*  length = (const int*)d_in[1];
    const void* ptime  = d_in[2];
    const void* wih    = d_in[3];
    const void* whh    = d_in[4];
    const void* bih    = d_in[5];
    const void* bhh    = d_in[6];

    const int B = in_sizes[1];   // 4096
    trend_encoder_kernel<<<dim3(B / ROWS), dim3(THREADS), 0, stream>>>(
        time_, length, ptime, wih, whh, bih, bhh, d_out);
}